// Round 1
// baseline (1166.112 us; speedup 1.0000x reference)
//
#include <hip/hip_runtime.h>
#include <hip/hip_bf16.h>
#include <math.h>

#define D_MODEL 1024
#define NHEADS  16
#define DH      64
#define SEQ     2048
#define BATCH   2

// ---------------- fold bilinear W into Wq ----------------
// Wq2[:, h*64+j] = sum_d Wq[:, h*64+d] * W[d][j]
__global__ __launch_bounds__(256) void fold_wq_kernel(const float* __restrict__ Wq,
                                                      const float* __restrict__ W,
                                                      float* __restrict__ Wq2) {
    int idx = blockIdx.x * 256 + threadIdx.x;   // over D*D
    int row = idx >> 10;
    int col = idx & 1023;
    int h = col >> 6, j = col & 63;
    const float* wqr = Wq + (size_t)row * D_MODEL + h * DH;
    float s = 0.f;
#pragma unroll
    for (int d = 0; d < DH; ++d) s += wqr[d] * W[d * DH + j];
    Wq2[idx] = s;
}

__global__ __launch_bounds__(256) void fold_bq_kernel(const float* __restrict__ bq,
                                                      const float* __restrict__ W,
                                                      float* __restrict__ bq2) {
    int col = blockIdx.x * 256 + threadIdx.x;
    if (col >= D_MODEL) return;
    int h = col >> 6, j = col & 63;
    float s = 0.f;
#pragma unroll
    for (int d = 0; d < DH; ++d) s += bq[h * DH + d] * W[d * DH + j];
    bq2[col] = s;
}

// ---------------- tiled fp32 GEMM: C = A(MxK) @ B(KxN) + bias ----------------
__global__ __launch_bounds__(256) void gemm_bias_kernel(const float* __restrict__ A,
                                                        const float* __restrict__ B,
                                                        const float* __restrict__ bias,
                                                        float* __restrict__ C,
                                                        int M, int N, int K) {
    __shared__ float sA[16][68];   // sA[kk][i] = A[r0+i][k0+kk]  (transposed)
    __shared__ float sB[16][64];   // sB[kk][j]
    const int t  = threadIdx.x;
    const int tx = t & 15, ty = t >> 4;
    const int r0 = blockIdx.y * 64, c0 = blockIdx.x * 64;

    const int ai  = t >> 2;          // 0..63 (A row within tile)
    const int ak4 = (t & 3) << 2;    // 0,4,8,12
    const int bk  = t >> 4;          // 0..15
    const int bj4 = (t & 15) << 2;   // 0..60

    float acc[4][4] = {};

    for (int k0 = 0; k0 < K; k0 += 16) {
        float4 a4 = *(const float4*)&A[(size_t)(r0 + ai) * K + k0 + ak4];
        float4 b4 = *(const float4*)&B[(size_t)(k0 + bk) * N + c0 + bj4];
        __syncthreads();
        sA[ak4 + 0][ai] = a4.x;
        sA[ak4 + 1][ai] = a4.y;
        sA[ak4 + 2][ai] = a4.z;
        sA[ak4 + 3][ai] = a4.w;
        *(float4*)&sB[bk][bj4] = b4;
        __syncthreads();
#pragma unroll
        for (int kk = 0; kk < 16; ++kk) {
            float4 av = *(float4*)&sA[kk][ty << 2];
            float4 bv = *(float4*)&sB[kk][tx << 2];
            float qa[4] = {av.x, av.y, av.z, av.w};
            float kb[4] = {bv.x, bv.y, bv.z, bv.w};
#pragma unroll
            for (int i = 0; i < 4; ++i)
#pragma unroll
                for (int j = 0; j < 4; ++j) acc[i][j] += qa[i] * kb[j];
        }
    }

#pragma unroll
    for (int i = 0; i < 4; ++i) {
        int r = r0 + (ty << 2) + i;
        int c = c0 + (tx << 2);
        float4 o;
        o.x = acc[i][0] + bias[c + 0];
        o.y = acc[i][1] + bias[c + 1];
        o.z = acc[i][2] + bias[c + 2];
        o.w = acc[i][3] + bias[c + 3];
        *(float4*)&C[(size_t)r * N + c] = o;
    }
}

// ---------------- flash-style bilinear attention (fp32) ----------------
// scores = Qp @ K^T per (b,h); masked keys (k >= thr) get score -1e-6 (NOT -inf).
__global__ __launch_bounds__(256) void attn_kernel(const float* __restrict__ Qp,
                                                   const float* __restrict__ Kp,
                                                   const float* __restrict__ Vp,
                                                   const int* __restrict__ thresholds,
                                                   float* __restrict__ AO) {
    __shared__ float sQT[DH][68];   // [d][q]
    __shared__ float sKT[DH][68];   // [d][k]
    __shared__ float sV[64][68];    // [k][d]
    __shared__ float sP[64][68];    // [q][k]  (probabilities)

    const int bh = blockIdx.y;
    const int b = bh >> 4, h = bh & 15;
    const int q0 = blockIdx.x * 64;
    const int t  = threadIdx.x;
    const int tx = t & 15, ty = t >> 4;
    const int thresh = thresholds[b];

    // stage Q tile transposed (lives whole kernel)
#pragma unroll
    for (int pass = 0; pass < 4; ++pass) {
        int r  = (t >> 4) + (pass << 4);           // 0..63
        int c4 = (t & 15) << 2;                    // 0..60
        const float4 q4 = *(const float4*)&Qp[((size_t)(b * SEQ + q0 + r)) * D_MODEL + h * DH + c4];
        sQT[c4 + 0][r] = q4.x;
        sQT[c4 + 1][r] = q4.y;
        sQT[c4 + 2][r] = q4.z;
        sQT[c4 + 3][r] = q4.w;
    }

    float m[4], l[4], O[4][4];
#pragma unroll
    for (int i = 0; i < 4; ++i) {
        m[i] = -INFINITY;
        l[i] = 0.f;
#pragma unroll
        for (int j = 0; j < 4; ++j) O[i][j] = 0.f;
    }

    for (int k0 = 0; k0 < SEQ; k0 += 64) {
        __syncthreads();   // prev PV readers done before restaging
#pragma unroll
        for (int pass = 0; pass < 4; ++pass) {
            int r  = (t >> 4) + (pass << 4);
            int c4 = (t & 15) << 2;
            size_t g = ((size_t)(b * SEQ + k0 + r)) * D_MODEL + h * DH + c4;
            float4 k4 = *(const float4*)&Kp[g];
            sKT[c4 + 0][r] = k4.x;
            sKT[c4 + 1][r] = k4.y;
            sKT[c4 + 2][r] = k4.z;
            sKT[c4 + 3][r] = k4.w;
            float4 v4 = *(const float4*)&Vp[g];
            *(float4*)&sV[r][c4] = v4;
        }
        __syncthreads();

        // scores: s[i][j] = sum_d Q[q0+ty*4+i][d] * K[k0+tx*4+j][d]
        float s[4][4] = {};
#pragma unroll
        for (int d = 0; d < DH; ++d) {
            float4 qv = *(float4*)&sQT[d][ty << 2];
            float4 kv = *(float4*)&sKT[d][tx << 2];
            float qa[4] = {qv.x, qv.y, qv.z, qv.w};
            float ka[4] = {kv.x, kv.y, kv.z, kv.w};
#pragma unroll
            for (int i = 0; i < 4; ++i)
#pragma unroll
                for (int j = 0; j < 4; ++j) s[i][j] += qa[i] * ka[j];
        }

        // mask (reference uses MASK_VALUE = -1e-6, still participates in softmax)
#pragma unroll
        for (int j = 0; j < 4; ++j) {
            int kg = k0 + (tx << 2) + j;
            if (kg >= thresh) {
                s[0][j] = -1e-6f; s[1][j] = -1e-6f; s[2][j] = -1e-6f; s[3][j] = -1e-6f;
            }
        }

        // online softmax per row (16 lanes share a row-group of 4 rows)
#pragma unroll
        for (int i = 0; i < 4; ++i) {
            float mt = fmaxf(fmaxf(s[i][0], s[i][1]), fmaxf(s[i][2], s[i][3]));
#pragma unroll
            for (int off = 1; off < 16; off <<= 1) mt = fmaxf(mt, __shfl_xor(mt, off));
            float mn = fmaxf(m[i], mt);
            float alpha = __expf(m[i] - mn);
            float rs = 0.f;
#pragma unroll
            for (int j = 0; j < 4; ++j) {
                float p = __expf(s[i][j] - mn);
                s[i][j] = p;
                rs += p;
            }
#pragma unroll
            for (int off = 1; off < 16; off <<= 1) rs += __shfl_xor(rs, off);
            l[i] = l[i] * alpha + rs;
            m[i] = mn;
#pragma unroll
            for (int j = 0; j < 4; ++j) O[i][j] *= alpha;
            *(float4*)&sP[(ty << 2) + i][tx << 2] = make_float4(s[i][0], s[i][1], s[i][2], s[i][3]);
        }
        __syncthreads();

        // PV accumulate: O[i][j] += sum_k P[row_i][k] * V[k][col_j]
#pragma unroll
        for (int k4 = 0; k4 < 16; ++k4) {
            float4 pv[4];
#pragma unroll
            for (int i = 0; i < 4; ++i) pv[i] = *(float4*)&sP[(ty << 2) + i][k4 << 2];
            float pa[4][4];
#pragma unroll
            for (int i = 0; i < 4; ++i) {
                pa[i][0] = pv[i].x; pa[i][1] = pv[i].y; pa[i][2] = pv[i].z; pa[i][3] = pv[i].w;
            }
#pragma unroll
            for (int kk = 0; kk < 4; ++kk) {
                float4 vv = *(float4*)&sV[(k4 << 2) + kk][tx << 2];
                float va[4] = {vv.x, vv.y, vv.z, vv.w};
#pragma unroll
                for (int i = 0; i < 4; ++i)
#pragma unroll
                    for (int j = 0; j < 4; ++j) O[i][j] += pa[i][kk] * va[j];
            }
        }
    }

    // epilogue: normalize and store
#pragma unroll
    for (int i = 0; i < 4; ++i) {
        float inv = 1.0f / l[i];
        float4 o = make_float4(O[i][0] * inv, O[i][1] * inv, O[i][2] * inv, O[i][3] * inv);
        *(float4*)&AO[((size_t)(b * SEQ + q0 + (ty << 2) + i)) * D_MODEL + h * DH + (tx << 2)] = o;
    }
}

extern "C" void kernel_launch(void* const* d_in, const int* in_sizes, int n_in,
                              void* d_out, int out_size, void* d_ws, size_t ws_size,
                              hipStream_t stream) {
    const float* queries    = (const float*)d_in[0];
    const float* keys       = (const float*)d_in[1];
    const float* values     = (const float*)d_in[2];
    const int*   thresholds = (const int*)d_in[3];
    const float* Wq = (const float*)d_in[4];
    const float* bq = (const float*)d_in[5];
    const float* Wk = (const float*)d_in[6];
    const float* bk = (const float*)d_in[7];
    const float* Wv = (const float*)d_in[8];
    const float* bv = (const float*)d_in[9];
    const float* W  = (const float*)d_in[10];
    const float* Wo = (const float*)d_in[11];
    const float* bo = (const float*)d_in[12];
    float* out = (float*)d_out;

    float* ws  = (float*)d_ws;
    float* Wq2 = ws;                        // 1M floats
    float* bq2 = ws + (1 << 20);            // 1K floats
    float* Qp  = ws + (1 << 20) + 2048;     // 4M floats each below
    float* Kp  = Qp + (1 << 22);
    float* Vp  = Kp + (1 << 22);
    float* AO  = Vp + (1 << 22);

    fold_wq_kernel<<<4096, 256, 0, stream>>>(Wq, W, Wq2);
    fold_bq_kernel<<<4, 256, 0, stream>>>(bq, W, bq2);

    dim3 ggrid(16, 64);   // (N/64, M/64)
    gemm_bias_kernel<<<ggrid, 256, 0, stream>>>(queries, Wq2, bq2, Qp, 4096, 1024, 1024);
    gemm_bias_kernel<<<ggrid, 256, 0, stream>>>(keys,    Wk,  bk,  Kp, 4096, 1024, 1024);
    gemm_bias_kernel<<<ggrid, 256, 0, stream>>>(values,  Wv,  bv,  Vp, 4096, 1024, 1024);

    dim3 agrid(SEQ / 64, BATCH * NHEADS);
    attn_kernel<<<agrid, 256, 0, stream>>>(Qp, Kp, Vp, thresholds, AO);

    gemm_bias_kernel<<<ggrid, 256, 0, stream>>>(AO, Wo, bo, out, 4096, 1024, 1024);
}

// Round 2
// 279.874 us; speedup vs baseline: 4.1666x; 4.1666x over previous
//
#include <hip/hip_runtime.h>
#include <hip/hip_bf16.h>
#include <math.h>

#define D_MODEL 1024
#define NHEADS  16
#define DH      64
#define SEQ     2048
#define BATCH   2

typedef __attribute__((ext_vector_type(8))) short short8;
typedef __attribute__((ext_vector_type(4))) float f32x4;

#define AS1C(p) ((const __attribute__((address_space(1))) void*)(p))
#define AS3(p)  ((__attribute__((address_space(3))) void*)(p))

// ---------------- fold bilinear W into Wq (fp32) ----------------
__global__ __launch_bounds__(256) void fold_wq_kernel(const float* __restrict__ Wq,
                                                      const float* __restrict__ W,
                                                      float* __restrict__ Wq2) {
    int idx = blockIdx.x * 256 + threadIdx.x;   // over D*D
    int row = idx >> 10;
    int col = idx & 1023;
    int h = col >> 6, j = col & 63;
    const float* wqr = Wq + (size_t)row * D_MODEL + h * DH;
    float s = 0.f;
#pragma unroll
    for (int d = 0; d < DH; ++d) s += wqr[d] * W[d * DH + j];
    Wq2[idx] = s;
}

__global__ __launch_bounds__(256) void fold_bq_kernel(const float* __restrict__ bq,
                                                      const float* __restrict__ W,
                                                      float* __restrict__ bq2) {
    int col = blockIdx.x * 256 + threadIdx.x;
    if (col >= D_MODEL) return;
    int h = col >> 6, j = col & 63;
    float s = 0.f;
#pragma unroll
    for (int d = 0; d < DH; ++d) s += bq[h * DH + d] * W[d * DH + j];
    bq2[col] = s;
}

// ---------------- fp32 -> bf16 (vectorized, 8/thread) ----------------
__global__ __launch_bounds__(256) void f32_to_bf16_kernel(const float* __restrict__ in,
                                                          __hip_bfloat16* __restrict__ out,
                                                          int n8) {
    int i = blockIdx.x * 256 + threadIdx.x;
    if (i >= n8) return;
    float4 a = *(const float4*)(in + (size_t)i * 8);
    float4 b = *(const float4*)(in + (size_t)i * 8 + 4);
    __hip_bfloat16 o[8];
    o[0] = __float2bfloat16(a.x); o[1] = __float2bfloat16(a.y);
    o[2] = __float2bfloat16(a.z); o[3] = __float2bfloat16(a.w);
    o[4] = __float2bfloat16(b.x); o[5] = __float2bfloat16(b.y);
    o[6] = __float2bfloat16(b.z); o[7] = __float2bfloat16(b.w);
    *(short8*)(out + (size_t)i * 8) = *(short8*)o;
}

// ---------------- transpose + convert: Win[K][N] fp32 -> Wt[N][K] bf16 ----------------
__global__ __launch_bounds__(256) void transpose_bf16_kernel(const float* __restrict__ Win,
                                                             __hip_bfloat16* __restrict__ Wt) {
    __shared__ float sT[32][33];
    int n0 = blockIdx.x * 32, k0 = blockIdx.y * 32;
    int tx = threadIdx.x & 31, ty = threadIdx.x >> 5;  // ty 0..7
#pragma unroll
    for (int i = 0; i < 4; ++i)
        sT[ty + i * 8][tx] = Win[(size_t)(k0 + ty + i * 8) * D_MODEL + n0 + tx];
    __syncthreads();
#pragma unroll
    for (int i = 0; i < 4; ++i)
        Wt[(size_t)(n0 + ty + i * 8) * D_MODEL + k0 + tx] = __float2bfloat16(sT[tx][ty + i * 8]);
}

// ---------------- bf16 MFMA GEMM: C = A[M][K] @ BT[N][K]^T + bias ----------------
// OUTMODE 0: bf16 out, head-separated [B][H][S][DH] layout
// OUTMODE 1: fp32 out, flat [M][N]
template<int OUTMODE>
__global__ __launch_bounds__(256) void gemm_bf16_kernel(
    const __hip_bfloat16* __restrict__ A,
    const __hip_bfloat16* __restrict__ BT,
    const float* __restrict__ bias,
    void* __restrict__ C,
    int M, int N, int K) {
    __shared__ __hip_bfloat16 sA[128 * 32];
    __shared__ __hip_bfloat16 sB[128 * 32];
    const int t = threadIdx.x;
    const int lane = t & 63;
    const int w = t >> 6;                // wave 0..3
    const int wr = (w >> 1) * 64;
    const int wc = (w & 1) * 64;
    const int r0 = blockIdx.y * 128;
    const int c0 = blockIdx.x * 128;

    f32x4 acc[4][4] = {};

    for (int k0 = 0; k0 < K; k0 += 32) {
        __syncthreads();
#pragma unroll
        for (int i = 0; i < 2; ++i) {
            int o = i * 4096 + w * 1024 + lane * 16;   // byte offset in 8KB tile
            int row = o >> 6;                          // 64B per row (32 bf16)
            int ce = (o & 63) >> 1;                    // element col
            __builtin_amdgcn_global_load_lds(AS1C(A + (size_t)(r0 + row) * K + k0 + ce),
                                             AS3((char*)sA + i * 4096 + w * 1024), 16, 0, 0);
            __builtin_amdgcn_global_load_lds(AS1C(BT + (size_t)(c0 + row) * K + k0 + ce),
                                             AS3((char*)sB + i * 4096 + w * 1024), 16, 0, 0);
        }
        __syncthreads();

        short8 af[4], bf[4];
#pragma unroll
        for (int m = 0; m < 4; ++m)
            af[m] = *(const short8*)(sA + (wr + m * 16 + (lane & 15)) * 32 + (lane >> 4) * 8);
#pragma unroll
        for (int n = 0; n < 4; ++n)
            bf[n] = *(const short8*)(sB + (wc + n * 16 + (lane & 15)) * 32 + (lane >> 4) * 8);
#pragma unroll
        for (int m = 0; m < 4; ++m)
#pragma unroll
            for (int n = 0; n < 4; ++n)
                acc[m][n] = __builtin_amdgcn_mfma_f32_16x16x32_bf16(af[m], bf[n], acc[m][n], 0, 0, 0);
    }

#pragma unroll
    for (int m = 0; m < 4; ++m) {
#pragma unroll
        for (int n = 0; n < 4; ++n) {
            int col = c0 + wc + n * 16 + (lane & 15);
            float bs = bias[col];
#pragma unroll
            for (int r = 0; r < 4; ++r) {
                int row = r0 + wr + m * 16 + (lane >> 4) * 4 + r;
                float v = acc[m][n][r] + bs;
                if (OUTMODE == 0) {
                    int b = row >> 11, s = row & 2047, h = col >> 6, d = col & 63;
                    ((__hip_bfloat16*)C)[(((size_t)(b * NHEADS + h)) * SEQ + s) * DH + d] =
                        __float2bfloat16(v);
                } else {
                    ((float*)C)[(size_t)row * N + col] = v;
                }
            }
        }
    }
}

// ---------------- flash MFMA attention ----------------
// Qp/Kp/Vp: [B*H][S][DH] bf16.  AO: [B*S][D_MODEL] bf16.
// Masked keys (k >= thresh) get score -1e-6 (still in softmax!).
__global__ __launch_bounds__(256) void attn_mfma_kernel(
    const __hip_bfloat16* __restrict__ Qp,
    const __hip_bfloat16* __restrict__ Kp,
    const __hip_bfloat16* __restrict__ Vp,
    const int* __restrict__ thresholds,
    __hip_bfloat16* __restrict__ AO) {
    __shared__ __hip_bfloat16 sK[64 * 64];    // [key][dh], slot-swizzled
    __shared__ __hip_bfloat16 sVT[64 * 64];   // [dh][key], slot-swizzled
    __shared__ __hip_bfloat16 sP[128 * 64];   // [q][key], slot-swizzled

    const int t = threadIdx.x, lane = t & 63, w = t >> 6;
    const int bh = blockIdx.y;
    const int b = bh >> 4, h = bh & 15;
    const int q0 = blockIdx.x * 128;
    const int thresh = thresholds[b];
    const __hip_bfloat16* Qb = Qp + (size_t)bh * SEQ * DH;
    const __hip_bfloat16* Kb = Kp + (size_t)bh * SEQ * DH;
    const __hip_bfloat16* Vb = Vp + (size_t)bh * SEQ * DH;

    // Q fragments in registers for whole kernel: wave owns q rows [w*32, w*32+32)
    short8 qf[2][2];
#pragma unroll
    for (int m = 0; m < 2; ++m)
#pragma unroll
        for (int kb = 0; kb < 2; ++kb) {
            int row = q0 + w * 32 + m * 16 + (lane & 15);
            int dh = kb * 32 + (lane >> 4) * 8;
            qf[m][kb] = *(const short8*)(Qb + (size_t)row * DH + dh);
        }

    f32x4 Oacc[2][4] = {};
    float mrow[2][4], lrow[2][4];
#pragma unroll
    for (int m = 0; m < 2; ++m)
#pragma unroll
        for (int r = 0; r < 4; ++r) { mrow[m][r] = -INFINITY; lrow[m][r] = 0.f; }

    for (int kv0 = 0; kv0 < SEQ; kv0 += 64) {
        __syncthreads();   // previous tile's PV reads done
        // --- stage K tile (8KB) via global_load_lds, pre-swizzled source ---
#pragma unroll
        for (int i = 0; i < 2; ++i) {
            int o = i * 4096 + w * 1024 + lane * 16;   // linear LDS byte pos
            int key = o >> 7;                          // 128B rows
            int slot = (o & 127) >> 4;                 // 16B slot 0..7
            int sslot = slot ^ (key & 7);              // inverse swizzle on source
            __builtin_amdgcn_global_load_lds(AS1C(Kb + (size_t)(kv0 + key) * DH + sslot * 8),
                                             AS3((char*)sK + i * 4096 + w * 1024), 16, 0, 0);
        }
        // --- stage V transposed into sVT (reg-staged, swizzled writes) ---
#pragma unroll
        for (int i = 0; i < 2; ++i) {
            int c = i * 256 + t;          // 0..511 chunks
            int key = c & 63;
            int dh0 = (c >> 6) * 8;
            short8 v = *(const short8*)(Vb + (size_t)(kv0 + key) * DH + dh0);
#pragma unroll
            for (int j = 0; j < 8; ++j) {
                int dh = dh0 + j;
                int sw = (dh * 128 + key * 2) ^ ((dh & 7) << 4);
                *(__hip_bfloat16*)((char*)sVT + sw) = ((const __hip_bfloat16*)&v)[j];
            }
        }
        __syncthreads();

        // --- QK^T: S[128][64], wave computes 32 q-rows ---
        f32x4 S[2][4] = {};
#pragma unroll
        for (int kb = 0; kb < 2; ++kb) {
            short8 kf[4];
#pragma unroll
            for (int n = 0; n < 4; ++n) {
                int key = n * 16 + (lane & 15);
                int slot = kb * 4 + (lane >> 4);
                int off = key * 128 + ((slot ^ (key & 7)) << 4);
                kf[n] = *(const short8*)((char*)sK + off);
            }
#pragma unroll
            for (int m = 0; m < 2; ++m)
#pragma unroll
                for (int n = 0; n < 4; ++n)
                    S[m][n] = __builtin_amdgcn_mfma_f32_16x16x32_bf16(qf[m][kb], kf[n], S[m][n], 0, 0, 0);
        }

        // --- mask: reference uses MASK_VALUE = -1e-6 (NOT -inf) ---
#pragma unroll
        for (int n = 0; n < 4; ++n) {
            int col = kv0 + n * 16 + (lane & 15);
            if (col >= thresh) {
#pragma unroll
                for (int m = 0; m < 2; ++m)
#pragma unroll
                    for (int r = 0; r < 4; ++r) S[m][n][r] = -1e-6f;
            }
        }

        // --- online softmax (rows split across 16-lane groups) ---
        float alpha[2][4];
#pragma unroll
        for (int m = 0; m < 2; ++m) {
#pragma unroll
            for (int r = 0; r < 4; ++r) {
                float mx = fmaxf(fmaxf(S[m][0][r], S[m][1][r]), fmaxf(S[m][2][r], S[m][3][r]));
#pragma unroll
                for (int off = 1; off < 16; off <<= 1) mx = fmaxf(mx, __shfl_xor(mx, off));
                float mn = fmaxf(mrow[m][r], mx);
                float a = __expf(mrow[m][r] - mn);
                float rs = 0.f;
#pragma unroll
                for (int n = 0; n < 4; ++n) {
                    float p = __expf(S[m][n][r] - mn);
                    S[m][n][r] = p;
                    rs += p;
                }
#pragma unroll
                for (int off = 1; off < 16; off <<= 1) rs += __shfl_xor(rs, off);
                lrow[m][r] = lrow[m][r] * a + rs;
                mrow[m][r] = mn;
                alpha[m][r] = a;
            }
        }
        // rescale O accumulators
#pragma unroll
        for (int m = 0; m < 2; ++m)
#pragma unroll
            for (int n = 0; n < 4; ++n)
#pragma unroll
                for (int r = 0; r < 4; ++r) Oacc[m][n][r] *= alpha[m][r];

        // --- write P to sP (bf16, swizzled) ---
#pragma unroll
        for (int m = 0; m < 2; ++m)
#pragma unroll
            for (int n = 0; n < 4; ++n)
#pragma unroll
                for (int r = 0; r < 4; ++r) {
                    int q = w * 32 + m * 16 + (lane >> 4) * 4 + r;
                    int key = n * 16 + (lane & 15);
                    int sw = (q * 128 + key * 2) ^ ((q & 7) << 4);
                    *(__hip_bfloat16*)((char*)sP + sw) = __float2bfloat16(S[m][n][r]);
                }
        __syncthreads();

        // --- PV: O += P[32 q][64 k] @ V[64 k][64 dh] ---
#pragma unroll
        for (int kb = 0; kb < 2; ++kb) {
            short8 pf[2], vf[4];
#pragma unroll
            for (int m = 0; m < 2; ++m) {
                int q = w * 32 + m * 16 + (lane & 15);
                int slot = kb * 4 + (lane >> 4);
                int off = q * 128 + ((slot ^ (q & 7)) << 4);
                pf[m] = *(const short8*)((char*)sP + off);
            }
#pragma unroll
            for (int n = 0; n < 4; ++n) {
                int dh = n * 16 + (lane & 15);
                int slot = kb * 4 + (lane >> 4);
                int off = dh * 128 + ((slot ^ (dh & 7)) << 4);
                vf[n] = *(const short8*)((char*)sVT + off);
            }
#pragma unroll
            for (int m = 0; m < 2; ++m)
#pragma unroll
                for (int n = 0; n < 4; ++n)
                    Oacc[m][n] = __builtin_amdgcn_mfma_f32_16x16x32_bf16(pf[m], vf[n], Oacc[m][n], 0, 0, 0);
        }
    }

    // --- epilogue: normalize, write bf16 to AO[B*S][D_MODEL] ---
#pragma unroll
    for (int m = 0; m < 2; ++m)
#pragma unroll
        for (int r = 0; r < 4; ++r) {
            float inv = 1.0f / lrow[m][r];
            int q = q0 + w * 32 + m * 16 + (lane >> 4) * 4 + r;
#pragma unroll
            for (int n = 0; n < 4; ++n) {
                int dh = n * 16 + (lane & 15);
                AO[((size_t)(b * SEQ + q)) * D_MODEL + h * DH + dh] =
                    __float2bfloat16(Oacc[m][n][r] * inv);
            }
        }
}

extern "C" void kernel_launch(void* const* d_in, const int* in_sizes, int n_in,
                              void* d_out, int out_size, void* d_ws, size_t ws_size,
                              hipStream_t stream) {
    const float* queries    = (const float*)d_in[0];
    const float* keys       = (const float*)d_in[1];
    const float* values     = (const float*)d_in[2];
    const int*   thresholds = (const int*)d_in[3];
    const float* Wq = (const float*)d_in[4];
    const float* bq = (const float*)d_in[5];
    const float* Wk = (const float*)d_in[6];
    const float* bk = (const float*)d_in[7];
    const float* Wv = (const float*)d_in[8];
    const float* bv = (const float*)d_in[9];
    const float* W  = (const float*)d_in[10];
    const float* Wo = (const float*)d_in[11];
    const float* bo = (const float*)d_in[12];
    float* out = (float*)d_out;

    char* wsb = (char*)d_ws;
    float* Wq2 = (float*)wsb;                          // 4 MB
    float* bq2 = (float*)(wsb + (4 << 20));            // 4 KB
    __hip_bfloat16* XqB = (__hip_bfloat16*)(wsb + (4 << 20) + 4096);
    __hip_bfloat16* XkB = XqB + (1 << 22);
    __hip_bfloat16* XvB = XkB + (1 << 22);
    __hip_bfloat16* WqT = XvB + (1 << 22);
    __hip_bfloat16* WkT = WqT + (1 << 20);
    __hip_bfloat16* WvT = WkT + (1 << 20);
    __hip_bfloat16* WoT = WvT + (1 << 20);
    __hip_bfloat16* QpB = WoT + (1 << 20);
    __hip_bfloat16* KpB = QpB + (1 << 22);
    __hip_bfloat16* VpB = KpB + (1 << 22);
    __hip_bfloat16* AOB = XqB;   // alias: XqB dead after Q projection

    const int M = BATCH * SEQ;   // 4096

    fold_wq_kernel<<<4096, 256, 0, stream>>>(Wq, W, Wq2);
    fold_bq_kernel<<<4, 256, 0, stream>>>(bq, W, bq2);

    int n8 = (M * D_MODEL) / 8;
    f32_to_bf16_kernel<<<(n8 + 255) / 256, 256, 0, stream>>>(queries, XqB, n8);
    f32_to_bf16_kernel<<<(n8 + 255) / 256, 256, 0, stream>>>(keys,    XkB, n8);
    f32_to_bf16_kernel<<<(n8 + 255) / 256, 256, 0, stream>>>(values,  XvB, n8);

    dim3 tgrid(32, 32);
    transpose_bf16_kernel<<<tgrid, 256, 0, stream>>>(Wq2, WqT);
    transpose_bf16_kernel<<<tgrid, 256, 0, stream>>>(Wk,  WkT);
    transpose_bf16_kernel<<<tgrid, 256, 0, stream>>>(Wv,  WvT);
    transpose_bf16_kernel<<<tgrid, 256, 0, stream>>>(Wo,  WoT);

    dim3 ggrid(D_MODEL / 128, M / 128);   // (8, 32)
    gemm_bf16_kernel<0><<<ggrid, 256, 0, stream>>>(XqB, WqT, bq2, QpB, M, D_MODEL, D_MODEL);
    gemm_bf16_kernel<0><<<ggrid, 256, 0, stream>>>(XkB, WkT, bk,  KpB, M, D_MODEL, D_MODEL);
    gemm_bf16_kernel<0><<<ggrid, 256, 0, stream>>>(XvB, WvT, bv,  VpB, M, D_MODEL, D_MODEL);

    dim3 agrid(SEQ / 128, BATCH * NHEADS);   // (16, 32)
    attn_mfma_kernel<<<agrid, 256, 0, stream>>>(QpB, KpB, VpB, thresholds, AOB);

    gemm_bf16_kernel<1><<<ggrid, 256, 0, stream>>>(AOB, WoT, bo, out, M, D_MODEL, D_MODEL);
}

// Round 3
// 218.266 us; speedup vs baseline: 5.3426x; 1.2823x over previous
//
#include <hip/hip_runtime.h>
#include <hip/hip_bf16.h>
#include <math.h>

#define D_MODEL 1024
#define NHEADS  16
#define DH      64
#define SEQ     2048
#define BATCH   2

typedef __attribute__((ext_vector_type(8))) short short8;
typedef __attribute__((ext_vector_type(4))) float f32x4;

#define AS1C(p) ((const __attribute__((address_space(1))) void*)(p))
#define AS3(p)  ((__attribute__((address_space(3))) void*)(p))

union PW { short8 s8; unsigned int u[4]; };

static __device__ __forceinline__ unsigned int pk2(float lo, float hi) {
    __hip_bfloat16 a = __float2bfloat16(lo), b = __float2bfloat16(hi);
    unsigned short au = *(unsigned short*)&a, bu = *(unsigned short*)&b;
    return (unsigned int)au | ((unsigned int)bu << 16);
}

// ---------------- fold bilinear W into Wq (fp32) ----------------
__global__ __launch_bounds__(256) void fold_wq_kernel(const float* __restrict__ Wq,
                                                      const float* __restrict__ W,
                                                      float* __restrict__ Wq2) {
    int idx = blockIdx.x * 256 + threadIdx.x;   // over D*D
    int row = idx >> 10;
    int col = idx & 1023;
    int h = col >> 6, j = col & 63;
    const float* wqr = Wq + (size_t)row * D_MODEL + h * DH;
    float s = 0.f;
#pragma unroll
    for (int d = 0; d < DH; ++d) s += wqr[d] * W[d * DH + j];
    Wq2[idx] = s;
}

__global__ __launch_bounds__(256) void fold_bq_kernel(const float* __restrict__ bq,
                                                      const float* __restrict__ W,
                                                      float* __restrict__ bq2) {
    int col = blockIdx.x * 256 + threadIdx.x;
    if (col >= D_MODEL) return;
    int h = col >> 6, j = col & 63;
    float s = 0.f;
#pragma unroll
    for (int d = 0; d < DH; ++d) s += bq[h * DH + d] * W[d * DH + j];
    bq2[col] = s;
}

// ---------------- fp32 -> bf16 (vectorized, 8/thread) ----------------
__global__ __launch_bounds__(256) void f32_to_bf16_kernel(const float* __restrict__ in,
                                                          __hip_bfloat16* __restrict__ out,
                                                          int n8) {
    int i = blockIdx.x * 256 + threadIdx.x;
    if (i >= n8) return;
    float4 a = *(const float4*)(in + (size_t)i * 8);
    float4 b = *(const float4*)(in + (size_t)i * 8 + 4);
    __hip_bfloat16 o[8];
    o[0] = __float2bfloat16(a.x); o[1] = __float2bfloat16(a.y);
    o[2] = __float2bfloat16(a.z); o[3] = __float2bfloat16(a.w);
    o[4] = __float2bfloat16(b.x); o[5] = __float2bfloat16(b.y);
    o[6] = __float2bfloat16(b.z); o[7] = __float2bfloat16(b.w);
    *(short8*)(out + (size_t)i * 8) = *(short8*)o;
}

// ---------------- transpose + convert: Win[K][N] fp32 -> Wt[N][K] bf16 ----------------
__global__ __launch_bounds__(256) void transpose_bf16_kernel(const float* __restrict__ Win,
                                                             __hip_bfloat16* __restrict__ Wt) {
    __shared__ float sT[32][33];
    int n0 = blockIdx.x * 32, k0 = blockIdx.y * 32;
    int tx = threadIdx.x & 31, ty = threadIdx.x >> 5;  // ty 0..7
#pragma unroll
    for (int i = 0; i < 4; ++i)
        sT[ty + i * 8][tx] = Win[(size_t)(k0 + ty + i * 8) * D_MODEL + n0 + tx];
    __syncthreads();
#pragma unroll
    for (int i = 0; i < 4; ++i)
        Wt[(size_t)(n0 + ty + i * 8) * D_MODEL + k0 + tx] = __float2bfloat16(sT[tx][ty + i * 8]);
}

// ---------------- bf16 MFMA GEMM (128x64 tile, 2-phase dbuf) ----------------
// C = A[M][K] @ BT[N][K]^T + bias
// OUTMODE 0: bf16 out, head-separated [B][H][S][DH]
// OUTMODE 1: fp32 out, flat [M][N]
// OUTMODE 2: bf16 out, head-separated TRANSPOSED [B][H][DH][S]  (for V)
template<int OUTMODE>
__global__ __launch_bounds__(256) void gemm_bf16_kernel(
    const __hip_bfloat16* __restrict__ A,
    const __hip_bfloat16* __restrict__ BT,
    const float* __restrict__ bias,
    void* __restrict__ C,
    int M, int N, int K) {
    __shared__ __hip_bfloat16 sA[2][128 * 32];
    __shared__ __hip_bfloat16 sB[2][64 * 32];
    const int t = threadIdx.x;
    const int lane = t & 63, w = t >> 6;
    const int g = lane >> 4, li = lane & 15;
    const int r0 = blockIdx.y * 128, c0 = blockIdx.x * 64;
    const int wr = (w >> 1) * 64, wc = (w & 1) * 32;

    f32x4 acc[4][2] = {};

    auto stage = [&](int bb, int k0) {
#pragma unroll
        for (int i = 0; i < 2; ++i) {
            int o = (i * 4 + w) * 1024 + lane * 16;
            int row = o >> 6, ce = (o & 63) >> 1;
            __builtin_amdgcn_global_load_lds(AS1C(A + (size_t)(r0 + row) * K + k0 + ce),
                                             AS3((char*)sA[bb] + (i * 4 + w) * 1024), 16, 0, 0);
        }
        {
            int o = w * 1024 + lane * 16;
            int row = o >> 6, ce = (o & 63) >> 1;
            __builtin_amdgcn_global_load_lds(AS1C(BT + (size_t)(c0 + row) * K + k0 + ce),
                                             AS3((char*)sB[bb] + w * 1024), 16, 0, 0);
        }
    };

    stage(0, 0);
    asm volatile("s_waitcnt vmcnt(0)" ::: "memory");
    __syncthreads();

    int cur = 0;
    for (int k0 = 0; k0 < K; k0 += 32) {
        if (k0 + 32 < K) stage(cur ^ 1, k0 + 32);
        short8 af[4], bf[2];
#pragma unroll
        for (int m = 0; m < 4; ++m)
            af[m] = *(const short8*)(sA[cur] + (wr + m * 16 + li) * 32 + g * 8);
#pragma unroll
        for (int n = 0; n < 2; ++n)
            bf[n] = *(const short8*)(sB[cur] + (wc + n * 16 + li) * 32 + g * 8);
#pragma unroll
        for (int m = 0; m < 4; ++m)
#pragma unroll
            for (int n = 0; n < 2; ++n)
                acc[m][n] = __builtin_amdgcn_mfma_f32_16x16x32_bf16(af[m], bf[n], acc[m][n], 0, 0, 0);
        asm volatile("s_waitcnt vmcnt(0)" ::: "memory");
        __syncthreads();
        cur ^= 1;
    }

#pragma unroll
    for (int m = 0; m < 4; ++m) {
#pragma unroll
        for (int n = 0; n < 2; ++n) {
            int col = c0 + wc + n * 16 + li;
            float bs = bias[col];
            int row0 = r0 + wr + m * 16 + g * 4;
            if (OUTMODE == 2) {
                int b = row0 >> 11, s0 = row0 & 2047;
                int h = col >> 6, d = col & 63;
                __hip_bfloat16 o4[4];
#pragma unroll
                for (int r = 0; r < 4; ++r) o4[r] = __float2bfloat16(acc[m][n][r] + bs);
                *(short4*)((__hip_bfloat16*)C + (((size_t)(b * NHEADS + h)) * DH + d) * SEQ + s0) =
                    *(short4*)o4;
            } else {
#pragma unroll
                for (int r = 0; r < 4; ++r) {
                    int row = row0 + r;
                    float v = acc[m][n][r] + bs;
                    if (OUTMODE == 0) {
                        int b = row >> 11, s = row & 2047, h = col >> 6, d = col & 63;
                        ((__hip_bfloat16*)C)[(((size_t)(b * NHEADS + h)) * SEQ + s) * DH + d] =
                            __float2bfloat16(v);
                    } else {
                        ((float*)C)[(size_t)row * N + col] = v;
                    }
                }
            }
        }
    }
}

// ---------------- flash MFMA attention (swapped QK^T, in-register softmax) ----------------
// Qp/Kp: [B*H][S][DH] bf16.  Vt: [B*H][DH][S] bf16.  AO: [B*S][D_MODEL] bf16.
// Masked keys (k >= thresh) get score -1e-6 (still participate in softmax!).
__global__ __launch_bounds__(128) void attn_mfma_kernel(
    const __hip_bfloat16* __restrict__ Qp,
    const __hip_bfloat16* __restrict__ Kp,
    const __hip_bfloat16* __restrict__ Vt,
    const int* __restrict__ thresholds,
    __hip_bfloat16* __restrict__ AO) {
    __shared__ char lds[32768];   // sK[2][8KB] | sVT[2][8KB]
    char* sK  = lds;
    char* sVT = lds + 16384;

    const int t = threadIdx.x, lane = t & 63, w = t >> 6;   // w in {0,1}
    const int g = lane >> 4, li = lane & 15;
    const int bh = blockIdx.y, b = bh >> 4, h = bh & 15;
    const int q0 = blockIdx.x * 64;
    const int thresh = thresholds[b];
    const __hip_bfloat16* Qb = Qp + (size_t)bh * SEQ * DH;
    const __hip_bfloat16* Kb = Kp + (size_t)bh * SEQ * DH;
    const __hip_bfloat16* Vb = Vt + (size_t)bh * DH * SEQ;

    // Q as B-fragments (col=q): qf[mq][kb], lane holds Q[q0+w*32+mq*16+li][kb*32+g*8 ..+8]
    short8 qf[2][2];
#pragma unroll
    for (int mq = 0; mq < 2; ++mq)
#pragma unroll
        for (int kb = 0; kb < 2; ++kb)
            qf[mq][kb] = *(const short8*)(Qb + (size_t)(q0 + w * 32 + mq * 16 + li) * DH +
                                          kb * 32 + g * 8);

    // O^T accumulators: col=q(li), row=dh=16n+4g+rr
    f32x4 Oacc[2][4] = {};
    float mrun[2] = {-INFINITY, -INFINITY};
    float lrun[2] = {0.f, 0.f};

    auto stageK = [&](int bb, int kv) {
#pragma unroll
        for (int i = 0; i < 4; ++i) {
            int o = i * 2048 + w * 1024 + lane * 16;
            int key = o >> 7, slot = (o & 127) >> 4;
            __builtin_amdgcn_global_load_lds(
                AS1C(Kb + (size_t)(kv + key) * DH + ((slot ^ (key & 7)) << 3)),
                AS3(sK + bb * 8192 + i * 2048 + w * 1024), 16, 0, 0);
        }
    };
    auto stageV = [&](int bb, int kv) {
#pragma unroll
        for (int i = 0; i < 4; ++i) {
            int o = i * 2048 + w * 1024 + lane * 16;
            int dh = o >> 7, slot = (o & 127) >> 4;
            __builtin_amdgcn_global_load_lds(
                AS1C(Vb + (size_t)dh * SEQ + kv + ((slot ^ (dh & 7)) << 3)),
                AS3(sVT + bb * 8192 + i * 2048 + w * 1024), 16, 0, 0);
        }
    };

    stageK(0, 0); stageV(0, 0);
    asm volatile("s_waitcnt vmcnt(0)" ::: "memory");
    __syncthreads();

    int cur = 0;
    for (int kv0 = 0; kv0 < SEQ; kv0 += 64) {
        if (kv0 + 64 < SEQ) { stageK(cur ^ 1, kv0 + 64); stageV(cur ^ 1, kv0 + 64); }

        // --- QK^T swapped: S^T[key][q] = mfma(A=K, B=Q) ---
        f32x4 S[2][4] = {};
#pragma unroll
        for (int kb = 0; kb < 2; ++kb) {
            short8 kf[4];
#pragma unroll
            for (int n = 0; n < 4; ++n) {
                int key = 16 * n + li;
                kf[n] = *(const short8*)(sK + cur * 8192 + key * 128 +
                                         (((4 * kb + g) ^ (key & 7)) << 4));
            }
#pragma unroll
            for (int mq = 0; mq < 2; ++mq)
#pragma unroll
                for (int n = 0; n < 4; ++n)
                    S[mq][n] = __builtin_amdgcn_mfma_f32_16x16x32_bf16(kf[n], qf[mq][kb],
                                                                       S[mq][n], 0, 0, 0);
        }

        // --- mask: key = kv0 + 16n + 4g + rr; MASK_VALUE = -1e-6 (NOT -inf) ---
        int tr = thresh - kv0 - 4 * g;
#pragma unroll
        for (int n = 0; n < 4; ++n)
#pragma unroll
            for (int rr = 0; rr < 4; ++rr)
                if (16 * n + rr >= tr) { S[0][n][rr] = -1e-6f; S[1][n][rr] = -1e-6f; }

        // --- per-lane row max (lane owns q=li; 16 in-lane + combine over g) ---
        float pmax[2];
#pragma unroll
        for (int mq = 0; mq < 2; ++mq) {
            float mx = S[mq][0][0];
#pragma unroll
            for (int n = 0; n < 4; ++n)
#pragma unroll
                for (int rr = 0; rr < 4; ++rr) mx = fmaxf(mx, S[mq][n][rr]);
            mx = fmaxf(mx, __shfl_xor(mx, 16));
            mx = fmaxf(mx, __shfl_xor(mx, 32));
            pmax[mq] = mx;
        }

        // --- defer-max (T13, THR=8): rescale only when max grew past threshold ---
        bool need = (pmax[0] > mrun[0] + 8.f) || (pmax[1] > mrun[1] + 8.f);
        if (__any(need)) {
#pragma unroll
            for (int mq = 0; mq < 2; ++mq) {
                float mn = fmaxf(mrun[mq], pmax[mq]);
                float alpha = __expf(mrun[mq] - mn);
                lrun[mq] *= alpha;
#pragma unroll
                for (int n = 0; n < 4; ++n)
#pragma unroll
                    for (int rr = 0; rr < 4; ++rr) Oacc[mq][n][rr] *= alpha;
                mrun[mq] = mn;
            }
        }

        // --- exp + rowsum + pack to bf16x2 words ---
        unsigned int pw[2][4][2];
#pragma unroll
        for (int mq = 0; mq < 2; ++mq) {
            float rs = 0.f;
#pragma unroll
            for (int n = 0; n < 4; ++n)
#pragma unroll
                for (int rr = 0; rr < 4; ++rr) {
                    float p = __expf(S[mq][n][rr] - mrun[mq]);
                    S[mq][n][rr] = p;
                    rs += p;
                }
            rs += __shfl_xor(rs, 16);
            rs += __shfl_xor(rs, 32);
            lrun[mq] += rs;
#pragma unroll
            for (int n = 0; n < 4; ++n)
#pragma unroll
                for (int rp = 0; rp < 2; ++rp)
                    pw[mq][n][rp] = pk2(S[mq][n][2 * rp], S[mq][n][2 * rp + 1]);
        }

        // --- redistribute P to PV B-fragments (in-register, no LDS) ---
        // target word w4 of pa[mq][kb]: keys 32kb+8g+2w4+{0,1}
        // source: lane (li + 16*(2(g&1)+(w4>>1))), word pw[2kb+(g>>1)][w4&1]
        short8 pa[2][2];
        const int h2 = g >> 1;
        const int srcbase = li + 32 * (g & 1);
#pragma unroll
        for (int mq = 0; mq < 2; ++mq)
#pragma unroll
            for (int kb = 0; kb < 2; ++kb) {
                PW u;
#pragma unroll
                for (int w4 = 0; w4 < 4; ++w4) {
                    int src = srcbase + 16 * (w4 >> 1);
                    int cA = __shfl((int)pw[mq][2 * kb][w4 & 1], src);
                    int cB = __shfl((int)pw[mq][2 * kb + 1][w4 & 1], src);
                    u.u[w4] = h2 ? (unsigned int)cB : (unsigned int)cA;
                }
                pa[mq][kb] = u.s8;
            }

        // --- PV: O^T[dh][q] += mfma(A=V^T, B=P^T) ---
#pragma unroll
        for (int kb = 0; kb < 2; ++kb) {
            short8 vf[4];
#pragma unroll
            for (int n = 0; n < 4; ++n) {
                int dh = 16 * n + li;
                vf[n] = *(const short8*)(sVT + cur * 8192 + dh * 128 +
                                         (((4 * kb + g) ^ (dh & 7)) << 4));
            }
#pragma unroll
            for (int mq = 0; mq < 2; ++mq)
#pragma unroll
                for (int n = 0; n < 4; ++n)
                    Oacc[mq][n] = __builtin_amdgcn_mfma_f32_16x16x32_bf16(vf[n], pa[mq][kb],
                                                                          Oacc[mq][n], 0, 0, 0);
        }

        asm volatile("s_waitcnt vmcnt(0)" ::: "memory");
        __syncthreads();
        cur ^= 1;
    }

    // --- epilogue: normalize, write bf16 (dh consecutive across rr -> 8B stores) ---
#pragma unroll
    for (int mq = 0; mq < 2; ++mq) {
        float linv = 1.0f / lrun[mq];
        int q = q0 + w * 32 + mq * 16 + li;
#pragma unroll
        for (int n = 0; n < 4; ++n) {
            __hip_bfloat16 o4[4];
#pragma unroll
            for (int rr = 0; rr < 4; ++rr) o4[rr] = __float2bfloat16(Oacc[mq][n][rr] * linv);
            *(short4*)(AO + (size_t)(b * SEQ + q) * D_MODEL + h * DH + 16 * n + 4 * g) =
                *(short4*)o4;
        }
    }
}

extern "C" void kernel_launch(void* const* d_in, const int* in_sizes, int n_in,
                              void* d_out, int out_size, void* d_ws, size_t ws_size,
                              hipStream_t stream) {
    const float* queries    = (const float*)d_in[0];
    const float* keys       = (const float*)d_in[1];
    const float* values     = (const float*)d_in[2];
    const int*   thresholds = (const int*)d_in[3];
    const float* Wq = (const float*)d_in[4];
    const float* bq = (const float*)d_in[5];
    const float* Wk = (const float*)d_in[6];
    const float* bk = (const float*)d_in[7];
    const float* Wv = (const float*)d_in[8];
    const float* bv = (const float*)d_in[9];
    const float* W  = (const float*)d_in[10];
    const float* Wo = (const float*)d_in[11];
    const float* bo = (const float*)d_in[12];
    float* out = (float*)d_out;

    char* wsb = (char*)d_ws;
    float* Wq2 = (float*)wsb;                          // 4 MB
    float* bq2 = (float*)(wsb + (4 << 20));            // 4 KB
    __hip_bfloat16* XqB = (__hip_bfloat16*)(wsb + (4 << 20) + 4096);
    __hip_bfloat16* XkB = XqB + (1 << 22);
    __hip_bfloat16* XvB = XkB + (1 << 22);
    __hip_bfloat16* WqT = XvB + (1 << 22);
    __hip_bfloat16* WkT = WqT + (1 << 20);
    __hip_bfloat16* WvT = WkT + (1 << 20);
    __hip_bfloat16* WoT = WvT + (1 << 20);
    __hip_bfloat16* QpB = WoT + (1 << 20);
    __hip_bfloat16* KpB = QpB + (1 << 22);
    __hip_bfloat16* VtB = KpB + (1 << 22);
    __hip_bfloat16* AOB = XqB;   // alias: XqB dead after Q projection

    const int M = BATCH * SEQ;   // 4096

    fold_wq_kernel<<<4096, 256, 0, stream>>>(Wq, W, Wq2);
    fold_bq_kernel<<<4, 256, 0, stream>>>(bq, W, bq2);

    int n8 = (M * D_MODEL) / 8;
    f32_to_bf16_kernel<<<(n8 + 255) / 256, 256, 0, stream>>>(queries, XqB, n8);
    f32_to_bf16_kernel<<<(n8 + 255) / 256, 256, 0, stream>>>(keys,    XkB, n8);
    f32_to_bf16_kernel<<<(n8 + 255) / 256, 256, 0, stream>>>(values,  XvB, n8);

    dim3 tgrid(32, 32);
    transpose_bf16_kernel<<<tgrid, 256, 0, stream>>>(Wq2, WqT);
    transpose_bf16_kernel<<<tgrid, 256, 0, stream>>>(Wk,  WkT);
    transpose_bf16_kernel<<<tgrid, 256, 0, stream>>>(Wv,  WvT);
    transpose_bf16_kernel<<<tgrid, 256, 0, stream>>>(Wo,  WoT);

    dim3 ggrid(D_MODEL / 64, M / 128);   // (16, 32) = 512 blocks
    gemm_bf16_kernel<0><<<ggrid, 256, 0, stream>>>(XqB, WqT, bq2, QpB, M, D_MODEL, D_MODEL);
    gemm_bf16_kernel<0><<<ggrid, 256, 0, stream>>>(XkB, WkT, bk,  KpB, M, D_MODEL, D_MODEL);
    gemm_bf16_kernel<2><<<ggrid, 256, 0, stream>>>(XvB, WvT, bv,  VtB, M, D_MODEL, D_MODEL);

    dim3 agrid(SEQ / 64, BATCH * NHEADS);   // (32, 32) = 1024 blocks
    attn_mfma_kernel<<<agrid, 128, 0, stream>>>(QpB, KpB, VtB, thresholds, AOB);

    gemm_bf16_kernel<1><<<ggrid, 256, 0, stream>>>(AOB, WoT, bo, out, M, D_MODEL, D_MODEL);
}

// Round 4
// 175.708 us; speedup vs baseline: 6.6366x; 1.2422x over previous
//
#include <hip/hip_runtime.h>
#include <hip/hip_bf16.h>
#include <math.h>

#define D_MODEL 1024
#define NHEADS  16
#define DH      64
#define SEQ     2048
#define BATCH   2

typedef __attribute__((ext_vector_type(8))) short short8;
typedef __attribute__((ext_vector_type(4))) float f32x4;

#define AS1C(p) ((const __attribute__((address_space(1))) void*)(p))
#define AS3(p)  ((__attribute__((address_space(3))) void*)(p))

union PW { short8 s8; unsigned int u[4]; };

static __device__ __forceinline__ unsigned int pk2(float lo, float hi) {
    __hip_bfloat16 a = __float2bfloat16(lo), b = __float2bfloat16(hi);
    unsigned short au = *(unsigned short*)&a, bu = *(unsigned short*)&b;
    return (unsigned int)au | ((unsigned int)bu << 16);
}

// ---------------- fold bilinear W into Wq + bq (fp32), single launch ----------------
__global__ __launch_bounds__(256) void fold_kernel(const float* __restrict__ Wq,
                                                   const float* __restrict__ bq,
                                                   const float* __restrict__ W,
                                                   float* __restrict__ Wq2,
                                                   float* __restrict__ bq2) {
    if (blockIdx.x < 4096) {
        int idx = blockIdx.x * 256 + threadIdx.x;   // over D*D
        int row = idx >> 10;
        int col = idx & 1023;
        int h = col >> 6, j = col & 63;
        const float* wqr = Wq + (size_t)row * D_MODEL + h * DH;
        float s = 0.f;
#pragma unroll
        for (int d = 0; d < DH; ++d) s += wqr[d] * W[d * DH + j];
        Wq2[idx] = s;
    } else {
        int col = (blockIdx.x - 4096) * 256 + threadIdx.x;
        int h = col >> 6, j = col & 63;
        float s = 0.f;
#pragma unroll
        for (int d = 0; d < DH; ++d) s += bq[h * DH + d] * W[d * DH + j];
        bq2[col] = s;
    }
}

// ---------------- fp32 -> bf16, all three inputs in one launch ----------------
__global__ __launch_bounds__(256) void convert3_kernel(const float* __restrict__ q,
                                                       const float* __restrict__ k,
                                                       const float* __restrict__ v,
                                                       __hip_bfloat16* __restrict__ oq,
                                                       __hip_bfloat16* __restrict__ ok,
                                                       __hip_bfloat16* __restrict__ ov) {
    int z = blockIdx.x >> 11;                      // 2048 blocks per array
    int i = (blockIdx.x & 2047) * 256 + threadIdx.x;
    const float* in = (z == 0) ? q : (z == 1) ? k : v;
    __hip_bfloat16* out = (z == 0) ? oq : (z == 1) ? ok : ov;
    float4 a = *(const float4*)(in + (size_t)i * 8);
    float4 b = *(const float4*)(in + (size_t)i * 8 + 4);
    __hip_bfloat16 o[8];
    o[0] = __float2bfloat16(a.x); o[1] = __float2bfloat16(a.y);
    o[2] = __float2bfloat16(a.z); o[3] = __float2bfloat16(a.w);
    o[4] = __float2bfloat16(b.x); o[5] = __float2bfloat16(b.y);
    o[6] = __float2bfloat16(b.z); o[7] = __float2bfloat16(b.w);
    *(short8*)(out + (size_t)i * 8) = *(short8*)o;
}

// ---------------- transpose+convert 4 weight matrices in one launch ----------------
__global__ __launch_bounds__(256) void transpose4_kernel(const float* __restrict__ W0,
                                                         const float* __restrict__ W1,
                                                         const float* __restrict__ W2,
                                                         const float* __restrict__ W3,
                                                         __hip_bfloat16* __restrict__ T0,
                                                         __hip_bfloat16* __restrict__ T1,
                                                         __hip_bfloat16* __restrict__ T2,
                                                         __hip_bfloat16* __restrict__ T3) {
    __shared__ float sT[32][33];
    int z = blockIdx.z;
    const float* Win = (z == 0) ? W0 : (z == 1) ? W1 : (z == 2) ? W2 : W3;
    __hip_bfloat16* Wt = (z == 0) ? T0 : (z == 1) ? T1 : (z == 2) ? T2 : T3;
    int n0 = blockIdx.x * 32, k0 = blockIdx.y * 32;
    int tx = threadIdx.x & 31, ty = threadIdx.x >> 5;  // ty 0..7
#pragma unroll
    for (int i = 0; i < 4; ++i)
        sT[ty + i * 8][tx] = Win[(size_t)(k0 + ty + i * 8) * D_MODEL + n0 + tx];
    __syncthreads();
#pragma unroll
    for (int i = 0; i < 4; ++i)
        Wt[(size_t)(n0 + ty + i * 8) * D_MODEL + k0 + tx] = __float2bfloat16(sT[tx][ty + i * 8]);
}

// ================= GEMM core (128x64 tile, BK=32, 2-phase dbuf) =================
// acc computed as C = A[M][1024] @ BT[N][1024]^T ; caller does epilogue.
#define GEMM_CORE(A_, BT_)                                                                  \
    __shared__ __hip_bfloat16 sA[2][128 * 32];                                              \
    __shared__ __hip_bfloat16 sB[2][64 * 32];                                               \
    const int t = threadIdx.x;                                                              \
    const int lane = t & 63, w = t >> 6;                                                    \
    const int g = lane >> 4, li = lane & 15;                                                \
    const int r0 = blockIdx.y * 128, c0 = blockIdx.x * 64;                                  \
    const int wr = (w >> 1) * 64, wc = (w & 1) * 32;                                        \
    f32x4 acc[4][2] = {};                                                                   \
    auto stage = [&](int bb, int k0) {                                                      \
        _Pragma("unroll")                                                                   \
        for (int i = 0; i < 2; ++i) {                                                       \
            int o = (i * 4 + w) * 1024 + lane * 16;                                         \
            int row = o >> 6, ce = (o & 63) >> 1;                                           \
            __builtin_amdgcn_global_load_lds(AS1C(A_ + (size_t)(r0 + row) * 1024 + k0 + ce),\
                                             AS3((char*)sA[bb] + (i * 4 + w) * 1024), 16, 0, 0); \
        }                                                                                   \
        {                                                                                   \
            int o = w * 1024 + lane * 16;                                                   \
            int row = o >> 6, ce = (o & 63) >> 1;                                           \
            __builtin_amdgcn_global_load_lds(AS1C(BT_ + (size_t)(c0 + row) * 1024 + k0 + ce),\
                                             AS3((char*)sB[bb] + w * 1024), 16, 0, 0);      \
        }                                                                                   \
    };                                                                                      \
    stage(0, 0);                                                                            \
    asm volatile("s_waitcnt vmcnt(0)" ::: "memory");                                        \
    __syncthreads();                                                                        \
    int cur = 0;                                                                            \
    for (int k0 = 0; k0 < 1024; k0 += 32) {                                                 \
        if (k0 + 32 < 1024) stage(cur ^ 1, k0 + 32);                                        \
        short8 af[4], bf[2];                                                                \
        _Pragma("unroll")                                                                   \
        for (int m = 0; m < 4; ++m)                                                         \
            af[m] = *(const short8*)(sA[cur] + (wr + m * 16 + li) * 32 + g * 8);            \
        _Pragma("unroll")                                                                   \
        for (int n = 0; n < 2; ++n)                                                         \
            bf[n] = *(const short8*)(sB[cur] + (wc + n * 16 + li) * 32 + g * 8);            \
        _Pragma("unroll")                                                                   \
        for (int m = 0; m < 4; ++m)                                                         \
            _Pragma("unroll")                                                               \
            for (int n = 0; n < 2; ++n)                                                     \
                acc[m][n] = __builtin_amdgcn_mfma_f32_16x16x32_bf16(af[m], bf[n], acc[m][n], 0, 0, 0); \
        asm volatile("s_waitcnt vmcnt(0)" ::: "memory");                                    \
        __syncthreads();                                                                    \
        cur ^= 1;                                                                           \
    }

// ---------------- QKV projections, one launch (grid.z selects which) ----------------
// z=0: Q -> Qp [B*H][S][DH];  z=1: K -> Kp same;  z=2: V -> Vt [B*H][DH][S]
__global__ __launch_bounds__(256) void gemm_qkv_kernel(
    const __hip_bfloat16* __restrict__ Xq, const __hip_bfloat16* __restrict__ Xk,
    const __hip_bfloat16* __restrict__ Xv,
    const __hip_bfloat16* __restrict__ WqT, const __hip_bfloat16* __restrict__ WkT,
    const __hip_bfloat16* __restrict__ WvT,
    const float* __restrict__ bq2, const float* __restrict__ bk, const float* __restrict__ bv,
    __hip_bfloat16* __restrict__ Qp, __hip_bfloat16* __restrict__ Kp,
    __hip_bfloat16* __restrict__ Vt) {
    const int z = blockIdx.z;
    const __hip_bfloat16* A  = (z == 0) ? Xq  : (z == 1) ? Xk  : Xv;
    const __hip_bfloat16* BT = (z == 0) ? WqT : (z == 1) ? WkT : WvT;
    const float* bias        = (z == 0) ? bq2 : (z == 1) ? bk  : bv;
    __hip_bfloat16* C        = (z == 0) ? Qp  : (z == 1) ? Kp  : Vt;

    GEMM_CORE(A, BT)

#pragma unroll
    for (int m = 0; m < 4; ++m) {
#pragma unroll
        for (int n = 0; n < 2; ++n) {
            int col = c0 + wc + n * 16 + li;
            float bs = bias[col];
            int row0 = r0 + wr + m * 16 + g * 4;
            int h = col >> 6, d = col & 63;
            if (z == 2) {
                int b = row0 >> 11, s0 = row0 & 2047;
                __hip_bfloat16 o4[4];
#pragma unroll
                for (int r = 0; r < 4; ++r) o4[r] = __float2bfloat16(acc[m][n][r] + bs);
                *(short4*)(C + (((size_t)(b * NHEADS + h)) * DH + d) * SEQ + s0) = *(short4*)o4;
            } else {
#pragma unroll
                for (int r = 0; r < 4; ++r) {
                    int row = row0 + r;
                    int b = row >> 11, s = row & 2047;
                    C[(((size_t)(b * NHEADS + h)) * SEQ + s) * DH + d] =
                        __float2bfloat16(acc[m][n][r] + bs);
                }
            }
        }
    }
}

// ---------------- output projection (fp32 out) ----------------
__global__ __launch_bounds__(256) void gemm_out_kernel(
    const __hip_bfloat16* __restrict__ A, const __hip_bfloat16* __restrict__ BT,
    const float* __restrict__ bias, float* __restrict__ C) {
    GEMM_CORE(A, BT)
#pragma unroll
    for (int m = 0; m < 4; ++m) {
#pragma unroll
        for (int n = 0; n < 2; ++n) {
            int col = c0 + wc + n * 16 + li;
            float bs = bias[col];
            int row0 = r0 + wr + m * 16 + g * 4;
#pragma unroll
            for (int r = 0; r < 4; ++r)
                C[(size_t)(row0 + r) * D_MODEL + col] = acc[m][n][r] + bs;
        }
    }
}

// ---------------- flash MFMA attention (swapped QK^T, threshold-aware) ----------------
// Qp/Kp: [B*H][S][DH] bf16.  Vt: [B*H][DH][S] bf16.  AO: [B*S][D_MODEL] bf16.
// Masked keys (k >= thresh) get score -1e-6 (still participate in softmax!).
// thresh is block-uniform -> three wave-uniform tile cases:
//   kv0+64 <= thresh : no mask ops
//   kv0 >= thresh    : ALL scores = -1e-6 -> P is per-row constant; skip K load,
//                      QK MFMAs, exp/pack/redistribute entirely.
//   else             : straddle, full path with mask.
__global__ __launch_bounds__(128) void attn_mfma_kernel(
    const __hip_bfloat16* __restrict__ Qp,
    const __hip_bfloat16* __restrict__ Kp,
    const __hip_bfloat16* __restrict__ Vt,
    const int* __restrict__ thresholds,
    __hip_bfloat16* __restrict__ AO) {
    __shared__ char lds[32768];   // sK[2][8KB] | sVT[2][8KB]
    char* sK  = lds;
    char* sVT = lds + 16384;

    const int t = threadIdx.x, lane = t & 63, w = t >> 6;   // w in {0,1}
    const int g = lane >> 4, li = lane & 15;
    const int bh = blockIdx.y, b = bh >> 4, h = bh & 15;
    const int q0 = blockIdx.x * 64;
    const int thresh = thresholds[b];
    const __hip_bfloat16* Qb = Qp + (size_t)bh * SEQ * DH;
    const __hip_bfloat16* Kb = Kp + (size_t)bh * SEQ * DH;
    const __hip_bfloat16* Vb = Vt + (size_t)bh * DH * SEQ;

    // Q as B-fragments (col=q): lane holds Q[q0+w*32+mq*16+li][kb*32+g*8 ..+8]
    short8 qf[2][2];
#pragma unroll
    for (int mq = 0; mq < 2; ++mq)
#pragma unroll
        for (int kb = 0; kb < 2; ++kb)
            qf[mq][kb] = *(const short8*)(Qb + (size_t)(q0 + w * 32 + mq * 16 + li) * DH +
                                          kb * 32 + g * 8);

    // O^T accumulators: col=q(li), row=dh=16n+4g+rr
    f32x4 Oacc[2][4] = {};
    float mrun[2] = {-INFINITY, -INFINITY};
    float lrun[2] = {0.f, 0.f};

    auto stageK = [&](int bb, int kv) {
#pragma unroll
        for (int i = 0; i < 4; ++i) {
            int o = i * 2048 + w * 1024 + lane * 16;
            int key = o >> 7, slot = (o & 127) >> 4;
            __builtin_amdgcn_global_load_lds(
                AS1C(Kb + (size_t)(kv + key) * DH + ((slot ^ (key & 7)) << 3)),
                AS3(sK + bb * 8192 + i * 2048 + w * 1024), 16, 0, 0);
        }
    };
    auto stageV = [&](int bb, int kv) {
#pragma unroll
        for (int i = 0; i < 4; ++i) {
            int o = i * 2048 + w * 1024 + lane * 16;
            int dh = o >> 7, slot = (o & 127) >> 4;
            __builtin_amdgcn_global_load_lds(
                AS1C(Vb + (size_t)dh * SEQ + kv + ((slot ^ (dh & 7)) << 3)),
                AS3(sVT + bb * 8192 + i * 2048 + w * 1024), 16, 0, 0);
        }
    };

    stageK(0, 0); stageV(0, 0);
    asm volatile("s_waitcnt vmcnt(0)" ::: "memory");
    __syncthreads();

    int cur = 0;
    for (int kv0 = 0; kv0 < SEQ; kv0 += 64) {
        int nxt = kv0 + 64;
        if (nxt < SEQ) {
            if (nxt < thresh) stageK(cur ^ 1, nxt);   // skip K for fully-masked tiles
            stageV(cur ^ 1, nxt);
        }

        short8 pa[2][2];
        if (kv0 >= thresh) {
            // ---- fully-masked fast path: all scores = -1e-6 ----
            bool need = (-1e-6f > mrun[0] + 8.f) || (-1e-6f > mrun[1] + 8.f);
            if (__any(need)) {
#pragma unroll
                for (int mq = 0; mq < 2; ++mq) {
                    float mn = fmaxf(mrun[mq], -1e-6f);
                    float alpha = __expf(mrun[mq] - mn);
                    lrun[mq] *= alpha;
#pragma unroll
                    for (int n = 0; n < 4; ++n)
#pragma unroll
                        for (int rr = 0; rr < 4; ++rr) Oacc[mq][n][rr] *= alpha;
                    mrun[mq] = mn;
                }
            }
#pragma unroll
            for (int mq = 0; mq < 2; ++mq) {
                float p = __expf(-1e-6f - mrun[mq]);   // P is uniform; value at q=li (this lane)
                lrun[mq] += 64.f * p;
                unsigned int wd = pk2(p, p);
                PW u; u.u[0] = wd; u.u[1] = wd; u.u[2] = wd; u.u[3] = wd;
                pa[mq][0] = u.s8; pa[mq][1] = u.s8;
            }
        } else {
            // ---- QK^T swapped: S^T[key][q] = mfma(A=K, B=Q) ----
            f32x4 S[2][4] = {};
            __builtin_amdgcn_s_setprio(1);
#pragma unroll
            for (int kb = 0; kb < 2; ++kb) {
                short8 kf[4];
#pragma unroll
                for (int n = 0; n < 4; ++n) {
                    int key = 16 * n + li;
                    kf[n] = *(const short8*)(sK + cur * 8192 + key * 128 +
                                             (((4 * kb + g) ^ (key & 7)) << 4));
                }
#pragma unroll
                for (int mq = 0; mq < 2; ++mq)
#pragma unroll
                    for (int n = 0; n < 4; ++n)
                        S[mq][n] = __builtin_amdgcn_mfma_f32_16x16x32_bf16(kf[n], qf[mq][kb],
                                                                           S[mq][n], 0, 0, 0);
            }
            __builtin_amdgcn_s_setprio(0);

            if (kv0 + 64 > thresh) {
                // straddle tile only: key = kv0 + 16n + 4g + rr
                int tr = thresh - kv0 - 4 * g;
#pragma unroll
                for (int n = 0; n < 4; ++n)
#pragma unroll
                    for (int rr = 0; rr < 4; ++rr)
                        if (16 * n + rr >= tr) { S[0][n][rr] = -1e-6f; S[1][n][rr] = -1e-6f; }
            }

            // per-lane row max (lane owns q=li)
            float pmax[2];
#pragma unroll
            for (int mq = 0; mq < 2; ++mq) {
                float mx = S[mq][0][0];
#pragma unroll
                for (int n = 0; n < 4; ++n)
#pragma unroll
                    for (int rr = 0; rr < 4; ++rr) mx = fmaxf(mx, S[mq][n][rr]);
                mx = fmaxf(mx, __shfl_xor(mx, 16));
                mx = fmaxf(mx, __shfl_xor(mx, 32));
                pmax[mq] = mx;
            }

            // defer-max (T13, THR=8)
            bool need = (pmax[0] > mrun[0] + 8.f) || (pmax[1] > mrun[1] + 8.f);
            if (__any(need)) {
#pragma unroll
                for (int mq = 0; mq < 2; ++mq) {
                    float mn = fmaxf(mrun[mq], pmax[mq]);
                    float alpha = __expf(mrun[mq] - mn);
                    lrun[mq] *= alpha;
#pragma unroll
                    for (int n = 0; n < 4; ++n)
#pragma unroll
                        for (int rr = 0; rr < 4; ++rr) Oacc[mq][n][rr] *= alpha;
                    mrun[mq] = mn;
                }
            }

            // exp + rowsum + pack
            unsigned int pw[2][4][2];
#pragma unroll
            for (int mq = 0; mq < 2; ++mq) {
                float rs = 0.f;
#pragma unroll
                for (int n = 0; n < 4; ++n)
#pragma unroll
                    for (int rr = 0; rr < 4; ++rr) {
                        float p = __expf(S[mq][n][rr] - mrun[mq]);
                        S[mq][n][rr] = p;
                        rs += p;
                    }
                rs += __shfl_xor(rs, 16);
                rs += __shfl_xor(rs, 32);
                lrun[mq] += rs;
#pragma unroll
                for (int n = 0; n < 4; ++n)
#pragma unroll
                    for (int rp = 0; rp < 2; ++rp)
                        pw[mq][n][rp] = pk2(S[mq][n][2 * rp], S[mq][n][2 * rp + 1]);
            }

            // redistribute P to PV B-fragments (in-register)
            const int h2 = g >> 1;
            const int srcbase = li + 32 * (g & 1);
#pragma unroll
            for (int mq = 0; mq < 2; ++mq)
#pragma unroll
                for (int kb = 0; kb < 2; ++kb) {
                    PW u;
#pragma unroll
                    for (int w4 = 0; w4 < 4; ++w4) {
                        int src = srcbase + 16 * (w4 >> 1);
                        int cA = __shfl((int)pw[mq][2 * kb][w4 & 1], src);
                        int cB = __shfl((int)pw[mq][2 * kb + 1][w4 & 1], src);
                        u.u[w4] = h2 ? (unsigned int)cB : (unsigned int)cA;
                    }
                    pa[mq][kb] = u.s8;
                }
        }

        // ---- PV: O^T[dh][q] += mfma(A=V^T, B=P^T) ----
        __builtin_amdgcn_s_setprio(1);
#pragma unroll
        for (int kb = 0; kb < 2; ++kb) {
            short8 vf[4];
#pragma unroll
            for (int n = 0; n < 4; ++n) {
                int dh = 16 * n + li;
                vf[n] = *(const short8*)(sVT + cur * 8192 + dh * 128 +
                                         (((4 * kb + g) ^ (dh & 7)) << 4));
            }
#pragma unroll
            for (int mq = 0; mq < 2; ++mq)
#pragma unroll
                for (int n = 0; n < 4; ++n)
                    Oacc[mq][n] = __builtin_amdgcn_mfma_f32_16x16x32_bf16(vf[n], pa[mq][kb],
                                                                          Oacc[mq][n], 0, 0, 0);
        }
        __builtin_amdgcn_s_setprio(0);

        asm volatile("s_waitcnt vmcnt(0)" ::: "memory");
        __syncthreads();
        cur ^= 1;
    }

    // ---- epilogue: normalize, write bf16 (8B stores) ----
#pragma unroll
    for (int mq = 0; mq < 2; ++mq) {
        float linv = 1.0f / lrun[mq];
        int q = q0 + w * 32 + mq * 16 + li;
#pragma unroll
        for (int n = 0; n < 4; ++n) {
            __hip_bfloat16 o4[4];
#pragma unroll
            for (int rr = 0; rr < 4; ++rr) o4[rr] = __float2bfloat16(Oacc[mq][n][rr] * linv);
            *(short4*)(AO + (size_t)(b * SEQ + q) * D_MODEL + h * DH + 16 * n + 4 * g) =
                *(short4*)o4;
        }
    }
}

extern "C" void kernel_launch(void* const* d_in, const int* in_sizes, int n_in,
                              void* d_out, int out_size, void* d_ws, size_t ws_size,
                              hipStream_t stream) {
    const float* queries    = (const float*)d_in[0];
    const float* keys       = (const float*)d_in[1];
    const float* values     = (const float*)d_in[2];
    const int*   thresholds = (const int*)d_in[3];
    const float* Wq = (const float*)d_in[4];
    const float* bq = (const float*)d_in[5];
    const float* Wk = (const float*)d_in[6];
    const float* bk = (const float*)d_in[7];
    const float* Wv = (const float*)d_in[8];
    const float* bv = (const float*)d_in[9];
    const float* W  = (const float*)d_in[10];
    const float* Wo = (const float*)d_in[11];
    const float* bo = (const float*)d_in[12];
    float* out = (float*)d_out;

    char* wsb = (char*)d_ws;
    float* Wq2 = (float*)wsb;                          // 4 MB
    float* bq2 = (float*)(wsb + (4 << 20));            // 4 KB
    __hip_bfloat16* XqB = (__hip_bfloat16*)(wsb + (4 << 20) + 4096);
    __hip_bfloat16* XkB = XqB + (1 << 22);
    __hip_bfloat16* XvB = XkB + (1 << 22);
    __hip_bfloat16* WqT = XvB + (1 << 22);
    __hip_bfloat16* WkT = WqT + (1 << 20);
    __hip_bfloat16* WvT = WkT + (1 << 20);
    __hip_bfloat16* WoT = WvT + (1 << 20);
    __hip_bfloat16* QpB = WoT + (1 << 20);
    __hip_bfloat16* KpB = QpB + (1 << 22);
    __hip_bfloat16* VtB = KpB + (1 << 22);
    __hip_bfloat16* AOB = XqB;   // alias: XqB dead after Q projection

    fold_kernel<<<4100, 256, 0, stream>>>(Wq, bq, W, Wq2, bq2);
    convert3_kernel<<<6144, 256, 0, stream>>>(queries, keys, values, XqB, XkB, XvB);
    transpose4_kernel<<<dim3(32, 32, 4), 256, 0, stream>>>(Wq2, Wk, Wv, Wo,
                                                           WqT, WkT, WvT, WoT);

    gemm_qkv_kernel<<<dim3(16, 32, 3), 256, 0, stream>>>(XqB, XkB, XvB, WqT, WkT, WvT,
                                                         bq2, bk, bv, QpB, KpB, VtB);

    attn_mfma_kernel<<<dim3(32, 32), 128, 0, stream>>>(QpB, KpB, VtB, thresholds, AOB);

    gemm_out_kernel<<<dim3(16, 32), 256, 0, stream>>>(AOB, WoT, bo, out);
}